// Round 6
// baseline (299.461 us; speedup 1.0000x reference)
//
#include <hip/hip_runtime.h>

// 3x3 conv, stride 1, pad 1, NCHW/OIHW fp32. N=16, C=32, OC=32, H=W=256.
//
// R9: stream ablation. Evidence so far: per-generation time (~21us / 2
// blocks/CU) is invariant across 5 structural changes (VALU cut, duty
// cycle, store layout, store policy, wave concurrency); fills prove DRAM
// does 6.7 TB/s pure-write; no per-phase accounting reaches the measured
// time. Stop theorizing -> ablate (Common-mistake #8).
//  D1 V_noread  (MODE 1): x loads -> compile-time zeros, all else identical.
//  D2 V_nostore (MODE 2): global stores -> asm keep-alive (rule #17).
//  D3 V0        (MODE 0): exact R7 control, runs LAST -> correct output.
// Readout: conv rows >=79us land in top-5 (tell apart by FETCH vs WRITE);
// faster ones pinned by headline = 159(fills) + V_nr + V_ns + V0 + gaps.

constexpr int N_  = 16;
constexpr int C_  = 32;
constexpr int OC_ = 32;
constexpr int H_  = 256;
constexpr int W_  = 256;

constexpr int XSTR = 20;             // ushorts per wi: 32B data (16 ic) + 8B pad
constexpr int XROW = 258 * XSTR;     // ushorts per staged row (wi = w+1)
constexpr int WSTRD = 36;            // ushorts per (t9,oc): 64B data + 8B pad
constexpr int WELEMS = 9 * 32 * WSTRD;   // 10368 ushorts
constexpr int WBYTES = WELEMS * 2;       // 20736 B (= 1296 x 16B exactly)

typedef __attribute__((ext_vector_type(4)))  short short4v;
typedef __attribute__((ext_vector_type(8)))  short short8v;
typedef __attribute__((ext_vector_type(16))) float float16v;
typedef __attribute__((ext_vector_type(4)))  float floatx4;

static __device__ __forceinline__ unsigned short f2bf(float f) {
    unsigned int u = __float_as_uint(f);
    unsigned int r = (u + 0x7FFFu + ((u >> 16) & 1u)) >> 16;   // RNE
    return (unsigned short)r;
}

// one instruction: dst.lo16 = bf16(lo), dst.hi16 = bf16(hi)
static __device__ __forceinline__ unsigned cvtpk(float lo, float hi) {
    unsigned r;
    asm("v_cvt_pk_bf16_f32 %0, %1, %2" : "=v"(r) : "v"(lo), "v"(hi));
    return r;
}

static __device__ __forceinline__ short8v load8(const unsigned short* p) {
    // 8B-aligned: two ds_read_b64
    short4v lo = *(const short4v*)p;
    short4v hi = *(const short4v*)(p + 4);
    return __builtin_shufflevector(lo, hi, 0, 1, 2, 3, 4, 5, 6, 7);
}

// ---- prep: swizzled bf16 weight image, computed once per launch ----
__global__ void conv_w_prep(const float* __restrict__ wgt,
                            unsigned short* __restrict__ wp) {
    const int i = blockIdx.x * 256 + threadIdx.x;
    if (i >= OC_ * C_ * 9) return;
    const float v = wgt[i];
    const int oc  = i / 288;
    const int rem = i - oc * 288;
    const int ic  = rem / 9;
    const int t9  = rem - ic * 9;
    wp[(t9 * 32 + oc) * WSTRD + ic] = f2bf(v);
}

// MODE: 0 = full (R7 control), 1 = no-read (x loads -> zeros),
//       2 = no-store (global stores -> asm keep-alive)
template<bool USE_WS, int MODE>
__global__ __launch_bounds__(512, 4) void conv3x3_mfma_kernel(
    const float* __restrict__ x,     // [N][C][H][W]
    const float* __restrict__ wgt,   // [OC][C][3][3]
    const float* __restrict__ bias,  // [OC]
    const unsigned short* __restrict__ wpk,  // prepped weights (d_ws)
    float* __restrict__ out)         // [N][OC][H][W]
{
    __shared__ __align__(16) unsigned short ldsX[4 * XROW];   // 41,280 B
    __shared__ __align__(16) unsigned short ldsW[WELEMS];     // 20,736 B

    const int tid = threadIdx.x;

    // XCD-aware swizzle: 2048 blocks, 8 XCDs x 256 consecutive (n, h-pair).
    const int id = blockIdx.x;
    const int L  = (id & 7) * 256 + (id >> 3);
    const int n  = L >> 7;           // image 0..15
    const int h  = (L & 127) * 2;    // output rows h, h+1

    const int lane = tid & 63;
    const int wv   = tid >> 6;       // wave 0..7
    const int rsel = wv >> 2;        // output row select (0/1)
    const int col  = lane & 31;      // A: oc; B/D: w col
    const int qd   = lane >> 5;      // k-quad select
    const int w0a  = (wv & 3) * 64;
    const int w0b  = (wv & 3) * 64 + 32;

    // staging map: thread -> (staged row r4, w-pair wlo, ic-quad icq)
    const int r4  = tid >> 7;        // staged input row 0..3 (= h-1+r4)
    const int t7  = tid & 127;
    const int wlo = t7 & 31;         // w-pair lane
    const int icq = t7 >> 5;         // 0..3 (handles ic-pairs icq and icq+4)
    const size_t HW = (size_t)H_ * W_;

    // ---- issue half0 x loads first (earliest possible) ----
    float2 a0[4], a1[4], b0r[4], b1r[4];
    auto load_half = [&](int half) {
        const int icg0 = half * 16 + 2 * icq;
        const int icg1 = half * 16 + 2 * (icq + 4);
        const int hy = h - 1 + r4;
        const bool doload = (MODE != 1) && hy >= 0 && hy < H_;
        if (doload) {
            const float* pA0 = x + ((size_t)(n * C_ + icg0) * H_ + hy) * W_;
            const float* pA1 = pA0 + HW;
            const float* pB0 = x + ((size_t)(n * C_ + icg1) * H_ + hy) * W_;
            const float* pB1 = pB0 + HW;
            #pragma unroll
            for (int wb = 0; wb < 4; ++wb) {
                const int w = wb * 64 + 2 * wlo;
                a0[wb]  = *(const float2*)(pA0 + w);
                a1[wb]  = *(const float2*)(pA1 + w);
                b0r[wb] = *(const float2*)(pB0 + w);
                b1r[wb] = *(const float2*)(pB1 + w);
            }
        } else {
            #pragma unroll
            for (int wb = 0; wb < 4; ++wb) {
                a0[wb] = a1[wb] = b0r[wb] = b1r[wb] = make_float2(0.f, 0.f);
            }
        }
    };
    load_half(0);

    // ---- weight stage ----
    if (USE_WS) {
        const int4* src = (const int4*)wpk;
        int4* dstW = (int4*)&ldsW[0];
        #pragma unroll
        for (int i2 = 0; i2 < 3; ++i2) {
            const int idx = tid + i2 * 512;
            if (idx < WBYTES / 16) dstW[idx] = src[idx];
        }
    } else {
        for (int i = tid; i < OC_ * C_ * 9; i += 512) {
            const float v = wgt[i];
            const int oc  = i / 288;
            const int rem = i - oc * 288;
            const int ic  = rem / 9;
            const int t9  = rem - ic * 9;
            ldsW[(t9 * 32 + oc) * WSTRD + ic] = f2bf(v);
        }
    }

    // ---- acc init with bias (D row = oc mapping, verified in R2) ----
    float16v acc0, acc1;
    #pragma unroll
    for (int r = 0; r < 16; ++r) {
        const float bv = bias[(r & 3) + 8 * (r >> 2) + 4 * qd];
        acc0[r] = bv;
        acc1[r] = bv;
    }

    auto write_half = [&]() {
        unsigned short* dst = &ldsX[r4 * XROW];
        #pragma unroll
        for (int wb = 0; wb < 4; ++wb) {
            const int w = wb * 64 + 2 * wlo;
            *(unsigned*)&dst[(w + 1) * XSTR + 2 * icq]       = cvtpk(a0[wb].x,  a1[wb].x);
            *(unsigned*)&dst[(w + 2) * XSTR + 2 * icq]       = cvtpk(a0[wb].y,  a1[wb].y);
            *(unsigned*)&dst[(w + 1) * XSTR + 2 * (icq + 4)] = cvtpk(b0r[wb].x, b1r[wb].x);
            *(unsigned*)&dst[(w + 2) * XSTR + 2 * (icq + 4)] = cvtpk(b0r[wb].y, b1r[wb].y);
        }
    };

    auto mfma_half = [&](int half) {
        #pragma unroll
        for (int kh = 0; kh < 3; ++kh) {
            #pragma unroll
            for (int kw = 0; kw < 3; ++kw) {
                const int t9 = kh * 3 + kw;
                const short8v av =
                    load8(&ldsW[(t9 * 32 + col) * WSTRD + half * 16 + qd * 8]);
                const short8v bf0 =
                    load8(&ldsX[(rsel + kh) * XROW + (w0a + col + kw) * XSTR + qd * 8]);
                const short8v bf1 =
                    load8(&ldsX[(rsel + kh) * XROW + (w0b + col + kw) * XSTR + qd * 8]);
                acc0 = __builtin_amdgcn_mfma_f32_32x32x16_bf16(av, bf0, acc0, 0, 0, 0);
                acc1 = __builtin_amdgcn_mfma_f32_32x32x16_bf16(av, bf1, acc1, 0, 0, 0);
            }
        }
    };

    // ---- pack + write half0; halo zeros (persist across both halves) ----
    write_half();
    if (tid < 32) {
        const int r  = tid >> 3;                 // staged row 0..3
        const int q  = tid & 7;
        const int wi = (q & 4) ? 257 : 0;
        const int c  = q & 3;
        *(unsigned long long*)&ldsX[r * XROW + wi * XSTR + c * 4] = 0ull;
    }
    __syncthreads();                 // X0 + W staged

    // half1 loads fly under MFMA half0; barrier #2's vmcnt(0) drains them
    load_half(1);
    mfma_half(0);
    __syncthreads();                 // MFMA0 readers done (and half1 loads landed)

    write_half();
    __syncthreads();                 // X1 staged
    mfma_half(1);

    // ---- epilogue: LDS transpose -> contiguous 1KB NT row stores ----
    __syncthreads();                 // all frag reads of ldsX done
    float* scr = (float*)&ldsX[0];   // 32 KB scratch: [32 oc][256 w]
    #pragma unroll
    for (int rr = 0; rr < 2; ++rr) {
        if (rsel == rr) {            // wave-uniform branch
            #pragma unroll
            for (int r = 0; r < 16; ++r) {
                const int oc = (r & 3) + 8 * (r >> 2) + 4 * qd;
                scr[oc * 256 + w0a + col] = acc0[r];
                scr[oc * 256 + w0b + col] = acc1[r];
            }
        }
        __syncthreads();
        float* outp = out + (size_t)n * OC_ * HW + (size_t)(h + rr) * W_;
        #pragma unroll
        for (int k = 0; k < 4; ++k) {
            const int oc = wv * 4 + k;
            const floatx4 v = *(const floatx4*)&scr[oc * 256 + lane * 4];
            if (MODE == 2) {
                // keep scratch reads + accs live without an HBM write
                const float s = v[0] + v[1] + v[2] + v[3];
                asm volatile("" :: "v"(s));
            } else {
                floatx4* dp = (floatx4*)(outp + (size_t)oc * HW + lane * 4);
                __builtin_nontemporal_store(v, dp);
            }
        }
        if (rr == 0) __syncthreads();
    }
}

extern "C" void kernel_launch(void* const* d_in, const int* in_sizes, int n_in,
                              void* d_out, int out_size, void* d_ws, size_t ws_size,
                              hipStream_t stream) {
    const float* x    = (const float*)d_in[0];
    const float* wgt  = (const float*)d_in[1];
    const float* bias = (const float*)d_in[2];
    float* out        = (float*)d_out;

    dim3 grid(N_ * H_ / 2);   // 2048 blocks, full problem, each dispatch
    dim3 block(512);

    if (d_ws != nullptr && ws_size >= (size_t)WBYTES) {
        unsigned short* wp = (unsigned short*)d_ws;
        conv_w_prep<<<dim3(36), dim3(256), 0, stream>>>(wgt, wp);
        // D1: no-read ablation (writes deterministic garbage; overwritten)
        conv3x3_mfma_kernel<true, 1><<<grid, block, 0, stream>>>(x, wgt, bias, wp, out);
        // D2: no-store ablation (writes nothing)
        conv3x3_mfma_kernel<true, 2><<<grid, block, 0, stream>>>(x, wgt, bias, wp, out);
        // D3: full control (R7 config) -- runs LAST, produces correct output
        conv3x3_mfma_kernel<true, 0><<<grid, block, 0, stream>>>(x, wgt, bias, wp, out);
    } else {
        conv3x3_mfma_kernel<false, 0><<<grid, block, 0, stream>>>(x, wgt, bias, nullptr, out);
    }
}